// Round 7
// baseline (63.100 us; speedup 1.0000x reference)
//
#include <hip/hip_runtime.h>
#include <hip/hip_bf16.h>

#define NROWS 4096
#define DIM   1024
#define BT    128            // tile edge
#define BK    64             // K-step
#define NKT   (DIM / BK)     // 16 K-steps
#define NTB   (NROWS / BT)   // 32 tile-blocks per edge
#define NBLK  (NTB * (NTB + 1) / 2)   // 528 triangular tiles (528 % 8 == 0)
#define TEMP_INV 10.0f

typedef __bf16 bf16x8 __attribute__((ext_vector_type(8)));
typedef float  f32x4  __attribute__((ext_vector_type(4)));

__device__ __forceinline__ void gload16(const void* g, void* l) {
    __builtin_amdgcn_global_load_lds(
        (const __attribute__((address_space(1))) void*)g,
        (__attribute__((address_space(3))) void*)l, 16, 0, 0);
}

__device__ __forceinline__ unsigned short f2bf(float f) {
    __hip_bfloat16 h = __float2bfloat16(f);
    return *reinterpret_cast<unsigned short*>(&h);
}

// Stage one 32-row chunk (4 KB) of a 128x64 K-tile: 1 gload16/thread (256 thr).
// Linear LDS dest (m104); bank swizzle kg ^= r&7 applied by pre-swizzling the
// global source granule (rule 21; 0 conflicts verified R4/R6).
__device__ __forceinline__ void stage_chunk(const unsigned short* __restrict__ src,
                                            unsigned short* lds, int tid, int c) {
    const int p  = c * 256 + tid;        // granule (16B units) 0..1023
    const int r  = p >> 3;               // tile row (8 granules = 128B/row)
    const int kg = (p & 7) ^ (r & 7);    // logical k-granule held at p
    gload16(src + (size_t)r * DIM + kg * 8, lds + p * 8);
}

// Row-normalize fp32 -> bf16; zeroes this row's partial accumulators.
__global__ __launch_bounds__(256) void normalize_k(const float* __restrict__ pred,
                                                   unsigned short* __restrict__ xn,
                                                   float* __restrict__ posw,
                                                   float* __restrict__ denw) {
    const int row = blockIdx.x;
    const int tid = threadIdx.x;
    const float4 v = reinterpret_cast<const float4*>(pred + (size_t)row * DIM)[tid];
    float ss = v.x * v.x + v.y * v.y + v.z * v.z + v.w * v.w;
    #pragma unroll
    for (int off = 32; off; off >>= 1) ss += __shfl_xor(ss, off, 64);
    __shared__ float red[4];
    if ((tid & 63) == 0) red[tid >> 6] = ss;
    __syncthreads();
    const float tot = red[0] + red[1] + red[2] + red[3];
    const float scale = 1.0f / fmaxf(sqrtf(tot), 1e-8f);
    ushort4 o;
    o.x = f2bf(v.x * scale);
    o.y = f2bf(v.y * scale);
    o.z = f2bf(v.z * scale);
    o.w = f2bf(v.w * scale);
    reinterpret_cast<ushort4*>(xn + (size_t)row * DIM)[tid] = o;
    if (tid == 0) { posw[row] = 0.0f; denw[row] = 0.0f; }
}

#define BAR asm volatile("s_barrier" ::: "memory")

// Fused symmetric Gram-GEMM + contrastive epilogue, upper-triangular tiles.
// 128^2 tile, 4 waves (2x2 of 64x64), BK=64 double-buffer (64 KB LDS ->
// 2 blocks/CU).  Cross-block wave overlap (independent barrier domains)
// fills the MFMA pipe during the other block's stage/barrier stalls (m114).
// R4's proven counted-vmcnt schedule: stage(kt+1) -> vmcnt(8) -> BAR ->
// MFMA -> BAR.  Off-diagonal tiles emit column-side AND row-side (mirror)
// partials; diagonal tiles stage B = A (uniform ledger) and col-side only.
__global__ __launch_bounds__(256, 4) void fused_gram(
        const unsigned short* __restrict__ xn, const int* __restrict__ tgt,
        float* __restrict__ posw, float* __restrict__ denw) {
    __shared__ unsigned short As[2][BT * BK];   // 2 x 16 KB
    __shared__ unsigned short Bs[2][BT * BK];   // 2 x 16 KB  (64 KB total)

    // XCD-chunked bijective remap (528 % 8 == 0): XCD k gets 66 consecutive
    // logical tiles -> neighboring tiles (shared panels) share an L2.
    const int wgid = (blockIdx.x & 7) * (NBLK / 8) + (blockIdx.x >> 3);

    // Decode linear id -> (bi, bj), bi <= bj (scalar loop, SALU).
    int bi = 0, rem = wgid;
    while (rem >= NTB - bi) { rem -= NTB - bi; ++bi; }
    const int bj = bi + rem;
    const bool diag = (bi == bj);
    const int rowbase = bi * BT;
    const int colbase = bj * BT;

    const int tid = threadIdx.x;
    const int w   = tid >> 6;
    const int l   = tid & 63;
    const int wr  = w >> 1;      // 0..1 (row half: 64 rows)
    const int wc  = w & 1;       // 0..1 (col half: 64 cols)
    const int l15 = l & 15;
    const int kgl = l >> 4;      // 0..3

    const unsigned short* arow = xn + (size_t)rowbase * DIM;
    const unsigned short* bcol = xn + (size_t)colbase * DIM;   // == arow if diag

    f32x4 acc[4][4];
    #pragma unroll
    for (int i = 0; i < 4; ++i)
        #pragma unroll
        for (int j = 0; j < 4; ++j)
            acc[i][j] = (f32x4){0.f, 0.f, 0.f, 0.f};

    // Prologue: stage tile 0 (8 loads/thread).
    #pragma unroll
    for (int c = 0; c < 4; ++c) stage_chunk(arow, &As[0][0], tid, c);
    #pragma unroll
    for (int c = 0; c < 4; ++c) stage_chunk(bcol, &Bs[0][0], tid, c);

    for (int kt = 0; kt < NKT; ++kt) {
        const int cur = kt & 1;
        if (kt + 1 < NKT) {
            const unsigned short* ag = arow + (kt + 1) * BK;
            const unsigned short* bg = bcol + (kt + 1) * BK;
            #pragma unroll
            for (int c = 0; c < 4; ++c) stage_chunk(ag, &As[cur ^ 1][0], tid, c);
            #pragma unroll
            for (int c = 0; c < 4; ++c) stage_chunk(bg, &Bs[cur ^ 1][0], tid, c);
            asm volatile("s_waitcnt vmcnt(8)" ::: "memory");   // tile kt landed
        } else {
            asm volatile("s_waitcnt vmcnt(0)" ::: "memory");
        }
        BAR;

        const unsigned short* as = &As[cur][0];
        const unsigned short* bs = &Bs[cur][0];
        #pragma unroll
        for (int ks = 0; ks < 2; ++ks) {
            const int xk = ((ks * 4 + kgl) ^ (l15 & 7)) * 8;
            bf16x8 a[4], b[4];
            #pragma unroll
            for (int fi = 0; fi < 4; ++fi)
                a[fi] = *reinterpret_cast<const bf16x8*>(
                    &as[(wr * 64 + fi * 16 + l15) * 64 + xk]);
            #pragma unroll
            for (int fj = 0; fj < 4; ++fj)
                b[fj] = *reinterpret_cast<const bf16x8*>(
                    &bs[(wc * 64 + fj * 16 + l15) * 64 + xk]);
            __builtin_amdgcn_s_setprio(1);
            #pragma unroll
            for (int fi = 0; fi < 4; ++fi)
                #pragma unroll
                for (int fj = 0; fj < 4; ++fj)
                    acc[fi][fj] = __builtin_amdgcn_mfma_f32_16x16x32_bf16(
                        a[fi], b[fj], acc[fi][fj], 0, 0, 0);
            __builtin_amdgcn_s_setprio(0);
        }
        BAR;   // all reads of slot cur done before next iter overwrites it
    }

    // Fused epilogue.  C/D layout: col = lane&15, row = (lane>>4)*4 + q.
    int jc[4], tj[4];
    #pragma unroll
    for (int fj = 0; fj < 4; ++fj) {
        jc[fj] = colbase + wc * 64 + fj * 16 + l15;
        tj[fj] = tgt[jc[fj]];
    }
    float denc[4] = {0.f, 0.f, 0.f, 0.f};
    float posc[4] = {0.f, 0.f, 0.f, 0.f};

    #pragma unroll
    for (int fi = 0; fi < 4; ++fi) {
        const int ribase = rowbase + wr * 64 + fi * 16 + (l >> 4) * 4;
        const int4 tiv = *reinterpret_cast<const int4*>(&tgt[ribase]);
        const int tia[4] = {tiv.x, tiv.y, tiv.z, tiv.w};
        float denr[4] = {0.f, 0.f, 0.f, 0.f};
        float posr[4] = {0.f, 0.f, 0.f, 0.f};
        #pragma unroll
        for (int q = 0; q < 4; ++q) {
            const int gi = ribase + q;
            const int ti = tia[q];
            #pragma unroll
            for (int fj = 0; fj < 4; ++fj) {
                const float s  = acc[fi][fj][q];
                const float pc = fmaxf(s, 1e-10f);
                const float e  = __expf(TEMP_INV * pc);
                if (ti != tj[fj]) {
                    denc[fj] += e;
                    denr[q]  += e;
                } else if (gi != jc[fj]) {
                    posc[fj] += pc;
                    posr[q]  += pc;
                }
            }
        }
        if (!diag) {
            // Row-side (mirror): lanes sharing a row differ in bits 0-3.
            #pragma unroll
            for (int q = 0; q < 4; ++q) {
                #pragma unroll
                for (int off = 1; off < 16; off <<= 1) {
                    denr[q] += __shfl_xor(denr[q], off, 64);
                    posr[q] += __shfl_xor(posr[q], off, 64);
                }
            }
            if (l15 == 0) {
                #pragma unroll
                for (int q = 0; q < 4; ++q) {
                    atomicAdd(&denw[ribase + q], denr[q]);
                    atomicAdd(&posw[ribase + q], posr[q]);
                }
            }
        }
    }

    // Column-side: lanes sharing a column differ in bits 4-5.
    #pragma unroll
    for (int fj = 0; fj < 4; ++fj) {
        #pragma unroll
        for (int off = 16; off < 64; off <<= 1) {
            denc[fj] += __shfl_xor(denc[fj], off, 64);
            posc[fj] += __shfl_xor(posc[fj], off, 64);
        }
        if (l < 16) {
            atomicAdd(&denw[jc[fj]], denc[fj]);
            atomicAdd(&posw[jc[fj]], posc[fj]);
        }
    }
}

// Single-block finalize: LDS class histogram + per-column loss + direct store.
__global__ __launch_bounds__(1024) void finalize_k(const float* __restrict__ posw,
                                                   const float* __restrict__ denw,
                                                   const int* __restrict__ tgt,
                                                   float* __restrict__ out) {
    __shared__ int hist[128];
    __shared__ float red[16];
    const int tid = threadIdx.x;
    if (tid < 128) hist[tid] = 0;
    __syncthreads();
    const int4 t4 = reinterpret_cast<const int4*>(tgt)[tid];   // 4 targets/thread
    atomicAdd(&hist[t4.x], 1);
    atomicAdd(&hist[t4.y], 1);
    atomicAdd(&hist[t4.z], 1);
    atomicAdd(&hist[t4.w], 1);
    __syncthreads();
    const int ta[4] = {t4.x, t4.y, t4.z, t4.w};
    float v = 0.0f;
    #pragma unroll
    for (int q = 0; q < 4; ++q) {
        const int j = tid * 4 + q;
        const float d = fmaxf(denw[j], 1e-10f);
        const float c = (float)(hist[ta[q]] - 1);
        v += TEMP_INV * posw[j] - c * __logf(d);
    }
    #pragma unroll
    for (int off = 32; off; off >>= 1) v += __shfl_xor(v, off, 64);
    if ((tid & 63) == 0) red[tid >> 6] = v;
    __syncthreads();
    if (tid == 0) {
        float s = 0.0f;
        #pragma unroll
        for (int i = 0; i < 16; ++i) s += red[i];
        out[0] = -s * (1.0f / 4096.0f);
    }
}

extern "C" void kernel_launch(void* const* d_in, const int* in_sizes, int n_in,
                              void* d_out, int out_size, void* d_ws, size_t ws_size,
                              hipStream_t stream) {
    const float* pred = (const float*)d_in[0];
    const int*   tgt  = (const int*)d_in[1];
    float* out = (float*)d_out;

    unsigned short* xn = (unsigned short*)d_ws;                      // 8 MB bf16
    float* posw = (float*)((char*)d_ws + (size_t)NROWS * DIM * 2);
    float* denw = posw + NROWS;

    normalize_k<<<NROWS, 256, 0, stream>>>(pred, xn, posw, denw);

    fused_gram<<<NBLK, 256, 0, stream>>>(xn, tgt, posw, denw);       // 528 blocks

    finalize_k<<<1, 1024, 0, stream>>>(posw, denw, tgt, out);
}

// Round 8
// 61.155 us; speedup vs baseline: 1.0318x; 1.0318x over previous
//
#include <hip/hip_runtime.h>
#include <hip/hip_bf16.h>

#define NROWS 4096
#define DIM   1024
#define BT    256            // tile edge (256x256 per block)
#define BK    64             // K-step
#define NKT   (DIM / BK)     // 16 K-steps
#define NTB   (NROWS / BT)   // 16 tile-blocks per edge
#define NBLK  (NTB * (NTB + 1) / 2)   // 136 triangular tiles = 8 x 17
#define TEMP_INV 10.0f

typedef __bf16 bf16x8 __attribute__((ext_vector_type(8)));
typedef float  f32x4  __attribute__((ext_vector_type(4)));

__device__ __forceinline__ void gload16(const void* g, void* l) {
    __builtin_amdgcn_global_load_lds(
        (const __attribute__((address_space(1))) void*)g,
        (__attribute__((address_space(3))) void*)l, 16, 0, 0);
}

__device__ __forceinline__ unsigned short f2bf(float f) {
    __hip_bfloat16 h = __float2bfloat16(f);
    return *reinterpret_cast<unsigned short*>(&h);
}

// Stage one 256x64 bf16 K-tile (32 KB) into LDS, 4 x gload16 per thread
// (512 thr).  Linear LDS dest (m104); bank swizzle kg ^= r&7 applied by
// pre-swizzling the global source granule (rule 21; 0 conflicts @R4/R6).
__device__ __forceinline__ void stage_tile(const unsigned short* __restrict__ src,
                                           unsigned short* lds, int tid) {
    #pragma unroll
    for (int c = 0; c < 4; ++c) {
        const int p  = c * 512 + tid;        // granule (16B units) 0..2047
        const int r  = p >> 3;               // tile row (8 granules = 128B/row)
        const int kg = (p & 7) ^ (r & 7);    // logical k-granule held at p
        gload16(src + (size_t)r * DIM + kg * 8, lds + p * 8);
    }
}

// Row-normalize fp32 -> bf16; zeroes this row's partial accumulators.
__global__ __launch_bounds__(256) void normalize_k(const float* __restrict__ pred,
                                                   unsigned short* __restrict__ xn,
                                                   float* __restrict__ posw,
                                                   float* __restrict__ denw) {
    const int row = blockIdx.x;
    const int tid = threadIdx.x;
    const float4 v = reinterpret_cast<const float4*>(pred + (size_t)row * DIM)[tid];
    float ss = v.x * v.x + v.y * v.y + v.z * v.z + v.w * v.w;
    #pragma unroll
    for (int off = 32; off; off >>= 1) ss += __shfl_xor(ss, off, 64);
    __shared__ float red[4];
    if ((tid & 63) == 0) red[tid >> 6] = ss;
    __syncthreads();
    const float tot = red[0] + red[1] + red[2] + red[3];
    const float scale = 1.0f / fmaxf(sqrtf(tot), 1e-8f);
    ushort4 o;
    o.x = f2bf(v.x * scale);
    o.y = f2bf(v.y * scale);
    o.z = f2bf(v.z * scale);
    o.w = f2bf(v.w * scale);
    reinterpret_cast<ushort4*>(xn + (size_t)row * DIM)[tid] = o;
    if (tid == 0) { posw[row] = 0.0f; denw[row] = 0.0f; }
}

#define BAR asm volatile("s_barrier" ::: "memory")

// Fused symmetric Gram-GEMM + contrastive epilogue over the 136 upper-
// triangular 256^2 tiles.  R4's exact proven schedule (824 TF/eff at full
// grid): counted-vmcnt pipeline, 0-conflict swizzle, 8 waves (2M x 4N),
// per-wave output 128x64.  Traffic 268 -> 142 MB (the R4 wall was aggregate
// global-read bandwidth, ~6.4 TB/s).  Off-diag tiles also emit row-side
// (mirror) partials; diag tiles stage B = A (uniform ledger), col-side only.
__global__ __launch_bounds__(512, 2) void fused_gram(
        const unsigned short* __restrict__ xn, const int* __restrict__ tgt,
        float* __restrict__ posw, float* __restrict__ denw) {
    __shared__ unsigned short As[2][BT * BK];   // 2 x 32 KB
    __shared__ unsigned short Bs[2][BT * BK];   // 2 x 32 KB  (128 KB total)

    // XCD-chunked bijective remap (136 = 8 x 17): each XCD gets 17 consecutive
    // triangle ids -> same row-panel reused from its L2.
    const int wgid = (blockIdx.x & 7) * (NBLK / 8) + (blockIdx.x >> 3);

    // Decode linear id -> (bi, bj), bi <= bj (scalar loop, SALU).
    int bi = 0, rem = wgid;
    while (rem >= NTB - bi) { rem -= NTB - bi; ++bi; }
    const int bj = bi + rem;
    const bool diag = (bi == bj);
    const int rowbase = bi * BT;
    const int colbase = bj * BT;

    const int tid = threadIdx.x;
    const int w   = tid >> 6;
    const int l   = tid & 63;
    const int wr  = w >> 2;      // 0..1  (row half: 128 rows)
    const int wc  = w & 3;       // 0..3  (col quarter: 64 cols)
    const int l15 = l & 15;
    const int kgl = l >> 4;      // 0..3

    const unsigned short* arow = xn + (size_t)rowbase * DIM;
    const unsigned short* bcol = xn + (size_t)colbase * DIM;   // == arow if diag

    f32x4 acc[8][4];
    #pragma unroll
    for (int i = 0; i < 8; ++i)
        #pragma unroll
        for (int j = 0; j < 4; ++j)
            acc[i][j] = (f32x4){0.f, 0.f, 0.f, 0.f};

    // Prologue: stage K-tile 0 into slot 0 (8 loads/thread).
    stage_tile(arow, &As[0][0], tid);
    stage_tile(bcol, &Bs[0][0], tid);

    for (int kt = 0; kt < NKT; ++kt) {
        const int cur = kt & 1;
        if (kt + 1 < NKT) {
            stage_tile(arow + (kt + 1) * BK, &As[cur ^ 1][0], tid);
            stage_tile(bcol + (kt + 1) * BK, &Bs[cur ^ 1][0], tid);
            asm volatile("s_waitcnt vmcnt(8)" ::: "memory");   // tile kt landed
        } else {
            asm volatile("s_waitcnt vmcnt(0)" ::: "memory");
        }
        BAR;

        const unsigned short* as = &As[cur][0];
        const unsigned short* bs = &Bs[cur][0];
        #pragma unroll
        for (int ks = 0; ks < 2; ++ks) {
            const int xk = ((ks * 4 + kgl) ^ (l15 & 7)) * 8;
            bf16x8 a[8], b[4];
            #pragma unroll
            for (int fi = 0; fi < 8; ++fi)
                a[fi] = *reinterpret_cast<const bf16x8*>(
                    &as[(wr * 128 + fi * 16 + l15) * 64 + xk]);
            #pragma unroll
            for (int fj = 0; fj < 4; ++fj)
                b[fj] = *reinterpret_cast<const bf16x8*>(
                    &bs[(wc * 64 + fj * 16 + l15) * 64 + xk]);
            __builtin_amdgcn_s_setprio(1);
            #pragma unroll
            for (int fi = 0; fi < 8; ++fi)
                #pragma unroll
                for (int fj = 0; fj < 4; ++fj)
                    acc[fi][fj] = __builtin_amdgcn_mfma_f32_16x16x32_bf16(
                        a[fi], b[fj], acc[fi][fj], 0, 0, 0);
            __builtin_amdgcn_s_setprio(0);
        }
        BAR;   // all reads of slot cur done before next iter overwrites it
    }

    // Fused epilogue.  C/D layout: col = lane&15, row = (lane>>4)*4 + q.
    int jc[4], tj[4];
    #pragma unroll
    for (int fj = 0; fj < 4; ++fj) {
        jc[fj] = colbase + wc * 64 + fj * 16 + l15;
        tj[fj] = tgt[jc[fj]];
    }
    float denc[4] = {0.f, 0.f, 0.f, 0.f};
    float posc[4] = {0.f, 0.f, 0.f, 0.f};

    #pragma unroll
    for (int fi = 0; fi < 8; ++fi) {
        const int ribase = rowbase + wr * 128 + fi * 16 + (l >> 4) * 4;
        const int4 tiv = *reinterpret_cast<const int4*>(&tgt[ribase]);
        const int tia[4] = {tiv.x, tiv.y, tiv.z, tiv.w};
        float denr[4] = {0.f, 0.f, 0.f, 0.f};
        float posr[4] = {0.f, 0.f, 0.f, 0.f};
        #pragma unroll
        for (int q = 0; q < 4; ++q) {
            const int gi = ribase + q;
            const int ti = tia[q];
            #pragma unroll
            for (int fj = 0; fj < 4; ++fj) {
                const float s  = acc[fi][fj][q];
                const float pc = fmaxf(s, 1e-10f);
                const float e  = __expf(TEMP_INV * pc);
                if (ti != tj[fj]) {
                    denc[fj] += e;
                    denr[q]  += e;
                } else if (gi != jc[fj]) {
                    posc[fj] += pc;
                    posr[q]  += pc;
                }
            }
        }
        if (!diag) {
            // Row-side (mirror): within a wave, lanes sharing a row differ in
            // bits 0-3 (the fj sum is already in-register).  After the reduce,
            // lanes {0,16,32,48} hold rows ribase+0..3 for their q-group.
            #pragma unroll
            for (int q = 0; q < 4; ++q) {
                #pragma unroll
                for (int off = 1; off < 16; off <<= 1) {
                    denr[q] += __shfl_xor(denr[q], off, 64);
                    posr[q] += __shfl_xor(posr[q], off, 64);
                }
            }
            if (l15 == 0) {
                #pragma unroll
                for (int q = 0; q < 4; ++q) {
                    atomicAdd(&denw[ribase + q], denr[q]);
                    atomicAdd(&posw[ribase + q], posr[q]);
                }
            }
        }
    }

    // Column-side: lanes sharing a column differ in bits 4-5.
    #pragma unroll
    for (int fj = 0; fj < 4; ++fj) {
        #pragma unroll
        for (int off = 16; off < 64; off <<= 1) {
            denc[fj] += __shfl_xor(denc[fj], off, 64);
            posc[fj] += __shfl_xor(posc[fj], off, 64);
        }
        if (l < 16) {
            atomicAdd(&denw[jc[fj]], denc[fj]);
            atomicAdd(&posw[jc[fj]], posc[fj]);
        }
    }
}

// Single-block finalize: LDS class histogram + per-column loss + direct store.
__global__ __launch_bounds__(1024) void finalize_k(const float* __restrict__ posw,
                                                   const float* __restrict__ denw,
                                                   const int* __restrict__ tgt,
                                                   float* __restrict__ out) {
    __shared__ int hist[128];
    __shared__ float red[16];
    const int tid = threadIdx.x;
    if (tid < 128) hist[tid] = 0;
    __syncthreads();
    const int4 t4 = reinterpret_cast<const int4*>(tgt)[tid];   // 4 targets/thread
    atomicAdd(&hist[t4.x], 1);
    atomicAdd(&hist[t4.y], 1);
    atomicAdd(&hist[t4.z], 1);
    atomicAdd(&hist[t4.w], 1);
    __syncthreads();
    const int ta[4] = {t4.x, t4.y, t4.z, t4.w};
    float v = 0.0f;
    #pragma unroll
    for (int q = 0; q < 4; ++q) {
        const int j = tid * 4 + q;
        const float d = fmaxf(denw[j], 1e-10f);
        const float c = (float)(hist[ta[q]] - 1);
        v += TEMP_INV * posw[j] - c * __logf(d);
    }
    #pragma unroll
    for (int off = 32; off; off >>= 1) v += __shfl_xor(v, off, 64);
    if ((tid & 63) == 0) red[tid >> 6] = v;
    __syncthreads();
    if (tid == 0) {
        float s = 0.0f;
        #pragma unroll
        for (int i = 0; i < 16; ++i) s += red[i];
        out[0] = -s * (1.0f / 4096.0f);
    }
}

extern "C" void kernel_launch(void* const* d_in, const int* in_sizes, int n_in,
                              void* d_out, int out_size, void* d_ws, size_t ws_size,
                              hipStream_t stream) {
    const float* pred = (const float*)d_in[0];
    const int*   tgt  = (const int*)d_in[1];
    float* out = (float*)d_out;

    unsigned short* xn = (unsigned short*)d_ws;                      // 8 MB bf16
    float* posw = (float*)((char*)d_ws + (size_t)NROWS * DIM * 2);
    float* denw = posw + NROWS;

    normalize_k<<<NROWS, 256, 0, stream>>>(pred, xn, posw, denw);

    fused_gram<<<NBLK, 512, 0, stream>>>(xn, tgt, posw, denw);       // 136 blocks

    finalize_k<<<1, 1024, 0, stream>>>(posw, denw, tgt, out);
}

// Round 9
// 45.628 us; speedup vs baseline: 1.3829x; 1.3403x over previous
//
#include <hip/hip_runtime.h>
#include <hip/hip_bf16.h>

#define NROWS 4096
#define DIM   1024           // K elements; 1024 B/row in fp8
#define BT    256            // tile edge (256x256 per block)
#define BK    128            // K-step (fp8: 128 B = 128 elems)
#define NKT   (DIM / BK)     // 8 K-steps
#define NTB   (NROWS / BT)   // 16 tile-blocks per edge
#define TEMP_INV 10.0f
#define INV_S2 0.00390625f   // 1/256 (fp8 stored as 16*x)

typedef float f32x4 __attribute__((ext_vector_type(4)));
typedef long  fp8x8;         // 8 x e4m3 in 2 VGPRs

__device__ __forceinline__ void gload16(const void* g, void* l) {
    __builtin_amdgcn_global_load_lds(
        (const __attribute__((address_space(1))) void*)g,
        (__attribute__((address_space(3))) void*)l, 16, 0, 0);
}

// Stage one 256x128 fp8 K-tile (32 KB) into LDS, 4 x gload16 per thread
// (512 thr).  Linear LDS dest (m104); bank swizzle kg ^= r&7 applied by
// pre-swizzling the global source granule (rule 21; 0 conflicts @R4/R6/R8).
// Row = 128 B = 8 granules of 16 B — identical granule geometry to R4.
__device__ __forceinline__ void stage_tile(const unsigned char* __restrict__ src,
                                           unsigned char* lds, int tid) {
    #pragma unroll
    for (int c = 0; c < 4; ++c) {
        const int p  = c * 512 + tid;        // granule 0..2047
        const int r  = p >> 3;               // tile row 0..255
        const int kg = (p & 7) ^ (r & 7);    // logical k-granule held at p
        gload16(src + (size_t)r * DIM + kg * 16, lds + p * 16);
    }
}

// Row-normalize fp32 -> fp8 e4m3 scaled by 16 (puts ~N(0,1/1024) values
// mid-range); zeroes this row's partial accumulators.
__global__ __launch_bounds__(256) void normalize_k(const float* __restrict__ pred,
                                                   unsigned char* __restrict__ xn,
                                                   float* __restrict__ posw,
                                                   float* __restrict__ denw) {
    const int row = blockIdx.x;
    const int tid = threadIdx.x;
    const float4 v = reinterpret_cast<const float4*>(pred + (size_t)row * DIM)[tid];
    float ss = v.x * v.x + v.y * v.y + v.z * v.z + v.w * v.w;
    #pragma unroll
    for (int off = 32; off; off >>= 1) ss += __shfl_xor(ss, off, 64);
    __shared__ float red[4];
    if ((tid & 63) == 0) red[tid >> 6] = ss;
    __syncthreads();
    const float tot = red[0] + red[1] + red[2] + red[3];
    const float scale = 16.0f / fmaxf(sqrtf(tot), 1e-8f);
    int pk = __builtin_amdgcn_cvt_pk_fp8_f32(v.x * scale, v.y * scale, 0, false);
    pk     = __builtin_amdgcn_cvt_pk_fp8_f32(v.z * scale, v.w * scale, pk, true);
    reinterpret_cast<int*>(xn)[row * (DIM / 4) + tid] = pk;
    if (tid == 0) { posw[row] = 0.0f; denw[row] = 0.0f; }
}

#define BAR asm volatile("s_barrier" ::: "memory")

// Fused Gram-GEMM + contrastive epilogue.  Full 16x16 grid (256 blocks,
// 1/CU), 8 waves (2M x 4N), per-wave output 128x64.  R4's proven
// counted-vmcnt schedule, fp8 operands: same MFMA count, HALF the staged
// bytes -> the 64 KB in-flight window covers 2x the K per step (8 steps).
__global__ __launch_bounds__(512, 2) void fused_gram(
        const unsigned char* __restrict__ xn, const int* __restrict__ tgt,
        float* __restrict__ posw, float* __restrict__ denw) {
    __shared__ unsigned char As[2][BT * BK];   // 2 x 32 KB
    __shared__ unsigned char Bs[2][BT * BK];   // 2 x 32 KB  (128 KB total)

    const int bi = blockIdx.x >> 4;
    const int bj = blockIdx.x & 15;   // bj stride-16 -> same-XCD B-panel reuse
    const int rowbase = bi * BT;
    const int colbase = bj * BT;

    const int tid = threadIdx.x;
    const int w   = tid >> 6;
    const int l   = tid & 63;
    const int wr  = w >> 2;      // 0..1  (row half: 128 rows)
    const int wc  = w & 3;       // 0..3  (col quarter: 64 cols)
    const int l15 = l & 15;
    const int kgl = l >> 4;      // 0..3
    const int hb  = (kgl & 1) * 8;   // byte-half within a granule

    const unsigned char* arow = xn + (size_t)rowbase * DIM;
    const unsigned char* bcol = xn + (size_t)colbase * DIM;

    f32x4 acc[8][4];
    #pragma unroll
    for (int i = 0; i < 8; ++i)
        #pragma unroll
        for (int j = 0; j < 4; ++j)
            acc[i][j] = (f32x4){0.f, 0.f, 0.f, 0.f};

    // Hoisted per-fragment LDS byte offsets, minus the ks-dependent granule
    // term.  Fragment for k-slice ks: row*128 + ((ks*2 + (kgl>>1)) ^ (row&7))*16
    // + hb.  (row&7 == l15&7.)
    int rowA[8], rowB[4];
    #pragma unroll
    for (int fi = 0; fi < 8; ++fi) rowA[fi] = (wr * 128 + fi * 16 + l15) * 128;
    #pragma unroll
    for (int fj = 0; fj < 4; ++fj) rowB[fj] = (wc * 64 + fj * 16 + l15) * 128;
    const int swz = l15 & 7;
    const int gk  = kgl >> 1;

    // Prologue: stage K-tile 0 into slot 0 (8 loads/thread).
    stage_tile(arow, &As[0][0], tid);
    stage_tile(bcol, &Bs[0][0], tid);

    for (int kt = 0; kt < NKT; ++kt) {
        const int cur = kt & 1;
        if (kt + 1 < NKT) {
            stage_tile(arow + (kt + 1) * BK, &As[cur ^ 1][0], tid);
            stage_tile(bcol + (kt + 1) * BK, &Bs[cur ^ 1][0], tid);
            asm volatile("s_waitcnt vmcnt(8)" ::: "memory");   // tile kt landed
        } else {
            asm volatile("s_waitcnt vmcnt(0)" ::: "memory");
        }
        BAR;

        const unsigned char* as = &As[cur][0];
        const unsigned char* bs = &Bs[cur][0];
        #pragma unroll
        for (int ks = 0; ks < 4; ++ks) {
            const int xg = ((ks * 2 + gk) ^ swz) * 16 + hb;
            fp8x8 a[8], b[4];
            #pragma unroll
            for (int fi = 0; fi < 8; ++fi)
                a[fi] = *reinterpret_cast<const fp8x8*>(&as[rowA[fi] + xg]);
            #pragma unroll
            for (int fj = 0; fj < 4; ++fj)
                b[fj] = *reinterpret_cast<const fp8x8*>(&bs[rowB[fj] + xg]);
            __builtin_amdgcn_s_setprio(1);
            #pragma unroll
            for (int fi = 0; fi < 8; ++fi)
                #pragma unroll
                for (int fj = 0; fj < 4; ++fj)
                    acc[fi][fj] = __builtin_amdgcn_mfma_f32_16x16x32_fp8_fp8(
                        a[fi], b[fj], acc[fi][fj], 0, 0, 0);
            __builtin_amdgcn_s_setprio(0);
        }
        BAR;   // all reads of slot cur done before next iter overwrites it
    }

    // Fused epilogue (column-side only; full grid covers both (i,j),(j,i)).
    // C/D layout: col = lane&15, row = (lane>>4)*4 + q.  p = acc/256.
    int jc[4], tj[4];
    #pragma unroll
    for (int fj = 0; fj < 4; ++fj) {
        jc[fj] = colbase + wc * 64 + fj * 16 + l15;
        tj[fj] = tgt[jc[fj]];
    }
    float denc[4] = {0.f, 0.f, 0.f, 0.f};
    float posc[4] = {0.f, 0.f, 0.f, 0.f};

    #pragma unroll
    for (int fi = 0; fi < 8; ++fi) {
        const int ribase = rowbase + wr * 128 + fi * 16 + (l >> 4) * 4;
        const int4 tiv = *reinterpret_cast<const int4*>(&tgt[ribase]);
        const int tia[4] = {tiv.x, tiv.y, tiv.z, tiv.w};
        #pragma unroll
        for (int q = 0; q < 4; ++q) {
            const int gi = ribase + q;
            const int ti = tia[q];
            #pragma unroll
            for (int fj = 0; fj < 4; ++fj) {
                const float s  = acc[fi][fj][q] * INV_S2;
                const float pc = fmaxf(s, 1e-10f);
                const float e  = __expf(TEMP_INV * pc);
                if (ti != tj[fj]) {
                    denc[fj] += e;
                } else if (gi != jc[fj]) {
                    posc[fj] += pc;
                }
            }
        }
    }

    // Lanes sharing a column differ in bits 4-5.
    #pragma unroll
    for (int fj = 0; fj < 4; ++fj) {
        #pragma unroll
        for (int off = 16; off < 64; off <<= 1) {
            denc[fj] += __shfl_xor(denc[fj], off, 64);
            posc[fj] += __shfl_xor(posc[fj], off, 64);
        }
        if (l < 16) {
            atomicAdd(&denw[jc[fj]], denc[fj]);
            atomicAdd(&posw[jc[fj]], posc[fj]);
        }
    }
}

// Single-block finalize: LDS class histogram + per-column loss + direct store.
__global__ __launch_bounds__(1024) void finalize_k(const float* __restrict__ posw,
                                                   const float* __restrict__ denw,
                                                   const int* __restrict__ tgt,
                                                   float* __restrict__ out) {
    __shared__ int hist[128];
    __shared__ float red[16];
    const int tid = threadIdx.x;
    if (tid < 128) hist[tid] = 0;
    __syncthreads();
    const int4 t4 = reinterpret_cast<const int4*>(tgt)[tid];   // 4 targets/thread
    atomicAdd(&hist[t4.x], 1);
    atomicAdd(&hist[t4.y], 1);
    atomicAdd(&hist[t4.z], 1);
    atomicAdd(&hist[t4.w], 1);
    __syncthreads();
    const int ta[4] = {t4.x, t4.y, t4.z, t4.w};
    float v = 0.0f;
    #pragma unroll
    for (int q = 0; q < 4; ++q) {
        const int j = tid * 4 + q;
        const float d = fmaxf(denw[j], 1e-10f);
        const float c = (float)(hist[ta[q]] - 1);
        v += TEMP_INV * posw[j] - c * __logf(d);
    }
    #pragma unroll
    for (int off = 32; off; off >>= 1) v += __shfl_xor(v, off, 64);
    if ((tid & 63) == 0) red[tid >> 6] = v;
    __syncthreads();
    if (tid == 0) {
        float s = 0.0f;
        #pragma unroll
        for (int i = 0; i < 16; ++i) s += red[i];
        out[0] = -s * (1.0f / 4096.0f);
    }
}

extern "C" void kernel_launch(void* const* d_in, const int* in_sizes, int n_in,
                              void* d_out, int out_size, void* d_ws, size_t ws_size,
                              hipStream_t stream) {
    const float* pred = (const float*)d_in[0];
    const int*   tgt  = (const int*)d_in[1];
    float* out = (float*)d_out;

    unsigned char* xn = (unsigned char*)d_ws;                        // 4 MB fp8
    float* posw = (float*)((char*)d_ws + (size_t)NROWS * DIM);
    float* denw = posw + NROWS;

    normalize_k<<<NROWS, 256, 0, stream>>>(pred, xn, posw, denw);

    fused_gram<<<NTB * NTB, 512, 0, stream>>>(xn, tgt, posw, denw);  // 256 blocks

    finalize_k<<<1, 1024, 0, stream>>>(posw, denw, tgt, out);
}